// Round 1
// baseline (75.876 us; speedup 1.0000x reference)
//
#include <hip/hip_runtime.h>
#include <hip/hip_bf16.h>

#define IN_DIM  128
#define OUT_DIM 256
#define NUM_F   8
#define BATCH   1024
#define KDIM    1152   // 9*128 ; k = f*IN_DIM + i ; f=0..7 -> sin((f+1)x), f=8 -> silu plane

typedef __attribute__((ext_vector_type(8))) short short8;   // MFMA A/B frag (8 bf16)
typedef __attribute__((ext_vector_type(4))) float float4v;  // MFMA C/D frag / vec loads

static __device__ __forceinline__ unsigned pk2(float a, float b) {
    float2 t; t.x = a; t.y = b;
    __hip_bfloat162 h = __float22bfloat162_rn(t);   // v_cvt_pk_bf16_f32
    union { __hip_bfloat162 h; unsigned u; } v; v.h = h;
    return v.u;
}

// ---- prep: pack everything once per iteration into bf16 planes in d_ws ----
// blocks [0,128)   : W rows, n = bid*256+t = o*128+i
//   Wb[o][f*128+i] = coef[n][f] * scale_sp[n]   (f<8),   scale_base[n] (f=8)
// blocks [128,640) : X rows, idx = b*128+i
//   Xb[b][f*128+i] = sin((f+1)*x[b][i])         (f<8),   silu(x)       (f=8)
__global__ __launch_bounds__(256)
void prep_kernel(const float* __restrict__ x,
                 const float* __restrict__ coef,
                 const float* __restrict__ scale_sp,
                 const float* __restrict__ scale_base,
                 unsigned short* __restrict__ Wb,
                 unsigned short* __restrict__ Xb)
{
    const int t = threadIdx.x;
    const int bid = blockIdx.x;
    union { unsigned u; unsigned short h[2]; } p;

    if (bid < 128) {
        const int n = bid * 256 + t;          // o*128 + i
        const int o = n >> 7, i = n & 127;
        const float4v* cg = (const float4v*)(coef + (size_t)n * NUM_F);
        float4v c0 = cg[0], c1 = cg[1];
        const float sp = scale_sp[n];
        const float sb = scale_base[n];
        unsigned short* w = Wb + (size_t)o * KDIM + i;   // consecutive lanes -> consecutive i (coalesced per plane)
        p.u = pk2(c0.x * sp, c0.y * sp); w[0 * IN_DIM] = p.h[0]; w[1 * IN_DIM] = p.h[1];
        p.u = pk2(c0.z * sp, c0.w * sp); w[2 * IN_DIM] = p.h[0]; w[3 * IN_DIM] = p.h[1];
        p.u = pk2(c1.x * sp, c1.y * sp); w[4 * IN_DIM] = p.h[0]; w[5 * IN_DIM] = p.h[1];
        p.u = pk2(c1.z * sp, c1.w * sp); w[6 * IN_DIM] = p.h[0]; w[7 * IN_DIM] = p.h[1];
        p.u = pk2(sb, 0.f);              w[8 * IN_DIM] = p.h[0];
    } else {
        const int idx = (bid - 128) * 256 + t;   // b*128 + i
        const int b = idx >> 7, i = idx & 127;
        const float xv = x[idx];
        // sin((k)x): s_{k+1} = 2cos(x)*s_k - s_{k-1}, s0=0
        float s1 = __sinf(xv), cs = __cosf(xv);
        float c2 = cs + cs;
        float s2 = c2 * s1;
        float s3 = c2 * s2 - s1;
        float s4 = c2 * s3 - s2;
        float s5 = c2 * s4 - s3;
        float s6 = c2 * s5 - s4;
        float s7 = c2 * s6 - s5;
        float s8 = c2 * s7 - s6;
        float sil = xv / (1.f + __expf(-xv));
        unsigned short* xo = Xb + (size_t)b * KDIM + i;
        p.u = pk2(s1, s2);  xo[0 * IN_DIM] = p.h[0]; xo[1 * IN_DIM] = p.h[1];
        p.u = pk2(s3, s4);  xo[2 * IN_DIM] = p.h[0]; xo[3 * IN_DIM] = p.h[1];
        p.u = pk2(s5, s6);  xo[4 * IN_DIM] = p.h[0]; xo[5 * IN_DIM] = p.h[1];
        p.u = pk2(s7, s8);  xo[6 * IN_DIM] = p.h[0]; xo[7 * IN_DIM] = p.h[1];
        p.u = pk2(sil, 0.f); xo[8 * IN_DIM] = p.h[0];
    }
}

// ---- main: y[1024,256] = Xb[1024,1152] . Wb[256,1152]^T + bias ----
// Same proven structure as before (16x16 out tile, 4-wave K split, LDS reduce),
// but inner loop is now two 16B bf16 loads + 1 MFMA per K-step. K=1152 -> 9 steps/wave.
__global__ __launch_bounds__(256, 4)
void gemm_kernel(const unsigned short* __restrict__ Xb,
                 const unsigned short* __restrict__ Wb,
                 const float* __restrict__ bias_w,
                 float* __restrict__ y)
{
    __shared__ float4v red[3][64];
    const int t = threadIdx.x;
    const int o0 = blockIdx.x * 16;
    const int b0 = blockIdx.y * 16;
    const int wave = t >> 6, lane = t & 63;
    const int mrow = lane & 15, q = lane >> 4;
    const int nn = o0 + mrow;

    // A frag: lane holds A[m = lane&15][k = q*8 + j] ; B frag mirrors with n = lane&15
    const unsigned short* aP = Xb + (size_t)(b0 + mrow) * KDIM + wave * 288 + q * 8;
    const unsigned short* bP = Wb + (size_t)nn * KDIM + wave * 288 + q * 8;

    float4v acc = {0.f, 0.f, 0.f, 0.f};
    #pragma unroll
    for (int ks = 0; ks < 9; ++ks) {
        short8 a = *(const short8*)(aP + ks * 32);
        short8 b = *(const short8*)(bP + ks * 32);
        acc = __builtin_amdgcn_mfma_f32_16x16x32_bf16(a, b, acc, 0, 0, 0);
    }

    if (wave > 0) red[wave - 1][lane] = acc;
    __syncthreads();
    if (wave == 0) {
        float4v r0 = red[0][lane], r1 = red[1][lane], r2 = red[2][lane];
        acc.x += r0.x + r1.x + r2.x;
        acc.y += r0.y + r1.y + r2.y;
        acc.z += r0.z + r1.z + r2.z;
        acc.w += r0.w + r1.w + r2.w;

        // C/D layout: col = lane&15 (n), row = q*4 + reg (m)
        const float bias = bias_w[nn];
        #pragma unroll
        for (int r = 0; r < 4; ++r) {
            int brow = b0 + q * 4 + r;
            y[(size_t)brow * OUT_DIM + nn] = acc[r] + bias;
        }
    }
}

extern "C" void kernel_launch(void* const* d_in, const int* in_sizes, int n_in,
                              void* d_out, int out_size, void* d_ws, size_t ws_size,
                              hipStream_t stream) {
    const float* x          = (const float*)d_in[0];
    // d_in[1] = grid (arange+1) — folded into the sin recurrence
    const float* coef       = (const float*)d_in[2];
    const float* scale_sp   = (const float*)d_in[3];
    const float* scale_base = (const float*)d_in[4];
    const float* bias_w     = (const float*)d_in[5];
    float* y = (float*)d_out;

    unsigned short* Wb = (unsigned short*)d_ws;                       // 256*1152*2  = 576 KB
    unsigned short* Xb = Wb + (size_t)OUT_DIM * KDIM;                 // 1024*1152*2 = 2.25 MB

    prep_kernel<<<640, 256, 0, stream>>>(x, coef, scale_sp, scale_base, Wb, Xb);

    dim3 grid(OUT_DIM / 16, BATCH / 16);   // 16 x 64 = 1024 blocks -> 4 blocks/CU
    gemm_kernel<<<grid, 256, 0, stream>>>(Xb, Wb, bias_w, y);
}